// Round 1
// baseline (223.069 us; speedup 1.0000x reference)
//
#include <hip/hip_runtime.h>

// Problem constants (from reference)
#define GQ 13              // grid
#define AQ 5               // anchors
#define CQ 36              // classes
#define TQ 30              // targets per image
#define CH (5 + CQ)        // 41 channels
#define GG (GQ * GQ)       // 169 cells per plane
#define CELLS (AQ * GG)    // 845 cells per image
#define BLOCK 896          // 14 waves; covers 845 cells
#define NWAVES (BLOCK / 64)

// Layout: predictions[b, a, c, gj, gi] at ((b*A + a)*41 + c)*169 + (gj*13 + gi)
// Cell id within a batch: a*169 + gj*13 + gi  (== thread id here)

__global__ __launch_bounds__(BLOCK) void yolo_main(
    const float* __restrict__ pred,
    const float* __restrict__ target,
    double* __restrict__ acc)
{
    __shared__ int   s_cell[TQ];
    __shared__ float s_tc[TQ][4];
    __shared__ int   s_cls[TQ];
    __shared__ float s_red[3][NWAVES];

    const int b   = blockIdx.x;
    const int tid = threadIdx.x;

    // ---- per-target preprocessing (threads 0..29) ----
    if (tid < TQ) {
        const float* tg = target + ((size_t)b * TQ + tid) * 5;
        float x = tg[0], y = tg[1], w = tg[2], h = tg[3], c5 = tg[4];
        bool valid = (x + y + w + h + c5) != 0.0f;
        float gx = x * GQ, gy = y * GQ, gw = w * GQ, gh = h * GQ;
        int gi = (int)gx, gj = (int)gy;
        const float AW[5] = {1.08f, 3.42f, 6.63f, 9.42f, 16.62f};
        const float AH[5] = {1.19f, 4.41f, 11.38f, 5.11f, 10.52f};
        float best = -1.0f; int bn = 0;
        #pragma unroll
        for (int a = 0; a < AQ; a++) {
            float inter = fminf(gw, AW[a]) * fminf(gh, AH[a]);
            float un    = gw * gh + AW[a] * AH[a] - inter;
            float iou   = inter / (un + 1e-16f);
            if (iou > best) { best = iou; bn = a; }   // strict > == argmax first-wins
        }
        s_cell[tid]  = valid ? ((bn * GQ + gj) * GQ + gi) : -1;
        s_tc[tid][0] = gx - (float)gi;
        s_tc[tid][1] = gy - (float)gj;
        s_tc[tid][2] = logf(gw / AW[bn] + 1e-16f);
        s_tc[tid][3] = logf(gh / AH[bn] + 1e-16f);
        s_cls[tid]   = (int)c5;
    }
    __syncthreads();

    // ---- per-cell loss ----
    float lcoord = 0.0f, lconf = 0.0f, lclass = 0.0f;
    if (tid < CELLS) {
        int a   = tid / GG;
        int rem = tid - a * GG;
        const float* base = pred + ((size_t)(b * AQ + a) * CH) * GG + rem;

        // match this cell against the 30 targets (LDS broadcast reads).
        // tcoord: last write wins; label: min class among colliders (tclass argmax).
        bool obj = false; int minc = CQ;
        float tx = 0.f, ty = 0.f, tw = 0.f, th = 0.f;
        #pragma unroll
        for (int t = 0; t < TQ; t++) {
            if (s_cell[t] == tid) {
                obj = true;
                tx = s_tc[t][0]; ty = s_tc[t][1];
                tw = s_tc[t][2]; th = s_tc[t][3];
                minc = min(minc, s_cls[t]);
            }
        }
        int label = obj ? minc : 0;   // argmax of all-zeros tclass row -> 0

        // conf loss
        float p0  = base[0];
        float sig = 1.0f / (1.0f + __expf(-p0));
        if (obj) {
            float d = 5.0f * (sig - 1.0f);           // OBJ_SCALE*(sig - 1)
            lconf = d * d;
            // coord loss: only object cells (coord_mask==1 there)
            float d1 = base[1 * GG] - tx;
            float d2 = base[2 * GG] - ty;
            float d3 = base[3 * GG] - tw;
            float d4 = base[4 * GG] - th;
            lcoord = d1 * d1 + d2 * d2 + d3 * d3 + d4 * d4;
        } else {
            lconf = sig * sig;                       // NOOBJ_SCALE*sig - 0
        }

        // class loss: -log_softmax(logits)[label], every cell
        float v[CQ];
        float m = -3.0e38f, vl = 0.0f;
        #pragma unroll
        for (int c = 0; c < CQ; c++) {
            v[c] = base[(size_t)(5 + c) * GG];
            m = fmaxf(m, v[c]);
            vl = (c == label) ? v[c] : vl;           // static unroll -> cndmask, no scratch
        }
        float sum = 0.0f;
        #pragma unroll
        for (int c = 0; c < CQ; c++) sum += __expf(v[c] - m);
        lclass = -(vl - m - __logf(sum));
    }

    // ---- block reduction: wave shuffle then LDS ----
    #pragma unroll
    for (int off = 32; off > 0; off >>= 1) {
        lcoord += __shfl_down(lcoord, off, 64);
        lconf  += __shfl_down(lconf,  off, 64);
        lclass += __shfl_down(lclass, off, 64);
    }
    int wv = tid >> 6, ln = tid & 63;
    if (ln == 0) { s_red[0][wv] = lcoord; s_red[1][wv] = lconf; s_red[2][wv] = lclass; }
    __syncthreads();
    if (tid == 0) {
        float a0 = 0.f, a1 = 0.f, a2 = 0.f;
        #pragma unroll
        for (int w = 0; w < NWAVES; w++) { a0 += s_red[0][w]; a1 += s_red[1][w]; a2 += s_red[2][w]; }
        atomicAdd(acc + 0, (double)a0);
        atomicAdd(acc + 1, (double)a1);
        atomicAdd(acc + 2, (double)a2);
    }
}

__global__ void yolo_final(const double* __restrict__ acc, float* __restrict__ out, float Bf)
{
    double inv = 1.0 / (double)Bf;
    float fcoord = (float)(acc[0] * inv);   // COORD_SCALE = 1
    float fconf  = (float)(acc[1] * inv);
    float fclass = (float)(acc[2] * inv);   // CLASS_SCALE = 1
    out[0] = fcoord + fconf + fclass;
    out[1] = fcoord;
    out[2] = fconf;
    out[3] = fclass;
}

extern "C" void kernel_launch(void* const* d_in, const int* in_sizes, int n_in,
                              void* d_out, int out_size, void* d_ws, size_t ws_size,
                              hipStream_t stream)
{
    const float* pred   = (const float*)d_in[0];
    const float* target = (const float*)d_in[1];
    float*  out = (float*)d_out;
    double* acc = (double*)d_ws;

    int B = in_sizes[0] / (AQ * CH * GG);   // 1024

    hipMemsetAsync(d_ws, 0, 3 * sizeof(double), stream);
    yolo_main<<<B, BLOCK, 0, stream>>>(pred, target, acc);
    yolo_final<<<1, 1, 0, stream>>>(acc, out, (float)B);
}